// Round 5
// baseline (970.395 us; speedup 1.0000x reference)
//
#include <hip/hip_runtime.h>
#include <cmath>

#define CC 21
#define HH 512
#define WW 512
#define HWSZ (HH*WW)
#define CHW (CC*HWSZ)
#define NITERS 5
#define SBLOCKS 1024          // softmax_reduce blocks (256 thr each)
#define ROWF (CC*WW)          // 10752 floats per image row in HWC
#define HROWF (CC*256)        // 5376 floats per half row

struct K9 { float k[9]; };

// --- init: q[c,h,w] = unaries[h,w,c]; one block per row, LDS-staged ---
__launch_bounds__(512)
__global__ void init_q_kernel(const float* __restrict__ unaries, float* __restrict__ q) {
    __shared__ __align__(16) float lu[ROWF];
    int h = blockIdx.x, tx = threadIdx.x;
    const float4* src = (const float4*)(unaries + (size_t)h*ROWF);
    float4* dst = (float4*)lu;
    #pragma unroll
    for (int j = 0; j < 6; ++j) {
        int idx = j*512 + tx;
        if (idx < ROWF/4) dst[idx] = src[idx];
    }
    __syncthreads();
    #pragma unroll
    for (int c = 0; c < CC; ++c) q[c*HWSZ + h*WW + tx] = lu[tx*CC + c];
}

// spT[h*W + w] = sp_map[w*W + h]  (one-time; coalesced mask reads later)
__global__ void transpose_sp_kernel(const int* __restrict__ sp, int* __restrict__ spT) {
    int p = blockIdx.x*256 + threadIdx.x;
    int h = p >> 9, w = p & (WW - 1);
    spT[p] = sp[w*WW + h];
}

// M = CM @ (SKW + BKW)   (both blurs identical since theta_gamma==theta_beta)
__global__ void precomp_M_kernel(const float* __restrict__ skw, const float* __restrict__ bkw,
                                 const float* __restrict__ cm, float* __restrict__ M) {
    int i = blockIdx.x * blockDim.x + threadIdx.x;
    if (i >= CC*CC) return;
    int r = i / CC, k = i - r*CC;
    float a = 0.f;
    for (int j = 0; j < CC; ++j) a += cm[r*CC + j] * (skw[j*CC + k] + bkw[j*CC + k]);
    M[i] = a;
}

// softmax + fused sparse clique reduction.
// part layout: [SBLOCKS][44]: 0..20 sum1, 21..41 sum2, 42 n1, 43 n2
__launch_bounds__(256)
__global__ void softmax_reduce_kernel(const float* __restrict__ q, float* __restrict__ sm,
                                      const int* __restrict__ spT,
                                      const int* __restrict__ sp_indices, int iter,
                                      float* __restrict__ part) {
    __shared__ float acc[44];
    int tx = threadIdx.x;
    int p = blockIdx.x * 256 + tx;
    if (tx < 44) acc[tx] = 0.f;
    __syncthreads();

    float v[CC];
    float m = -1e30f;
    #pragma unroll
    for (int c = 0; c < CC; ++c) { v[c] = q[c*HWSZ + p]; m = fmaxf(m, v[c]); }
    float s = 0.f;
    #pragma unroll
    for (int c = 0; c < CC; ++c) { v[c] = expf(v[c] - m); s += v[c]; }
    float inv = 1.f / s;
    #pragma unroll
    for (int c = 0; c < CC; ++c) sm[c*HWSZ + p] = v[c] * inv;

    int idx = sp_indices[iter];
    int lab = spT[p];
    if (lab == idx || lab == idx + 1) {
        int mk = (lab == idx) ? 0 : 1;
        atomicAdd(&acc[42 + mk], 1.f);
        for (int c = 0; c < CC; ++c) atomicAdd(&acc[mk*21 + c], expf(v[c] * inv));
    }
    __syncthreads();
    if (tx < 44) part[blockIdx.x*44 + tx] = acc[tx];
}

// B[t] = log(HW - n_m + sum_m[c]),  t = m*21 + c
__launch_bounds__(256)
__global__ void finalize_kernel(const float* __restrict__ part, float* __restrict__ B) {
    __shared__ float sums[44][4];
    int t = threadIdx.x;
    int s = t >> 2, k = t & 3;
    if (s < 44) {
        float a = 0.f;
        for (int b = k; b < SBLOCKS; b += 4) a += part[b*44 + s];
        sums[s][k] = a;
    }
    __syncthreads();
    if (t < 42) {
        int m = t / 21;
        float n  = sums[42+m][0] + sums[42+m][1] + sums[42+m][2] + sums[42+m][3];
        float ss = sums[t][0] + sums[t][1] + sums[t][2] + sums[t][3];
        B[t] = logf((float)HWSZ - n + ss);
    }
}

// Fused: vblur (during tile staging, from sm) -> hblur -> /norm -> M@ ->
// attachment -> q = u - pw - att. Half-row blocks (256 px), 3 blocks/CU.
__launch_bounds__(256)
__global__ void final_kernel(const float* __restrict__ sm, float* __restrict__ qout,
                             float* __restrict__ outHWC,
                             const float* __restrict__ unaries,
                             const int* __restrict__ spT,
                             const int* __restrict__ sp_indices, int iter,
                             const float* __restrict__ Mg, const float* __restrict__ Bg,
                             const float* __restrict__ lwg, const float* __restrict__ hwg,
                             K9 kk, int last) {
    __shared__ __align__(16) float lu[HROWF];    // 21504 B (u half-row; out on last)
    __shared__ float tile[CC][264];              // 22176 B (v-blurred, w-haloed)
    __shared__ float Ms[CC*CC];
    __shared__ float Bs[2*CC], lws[2*CC], hws[2];

    int bid = blockIdx.x;                        // 0..1023
    int xcd = bid & 7, tt = bid >> 3;            // 128 blocks per XCD chunk
    int h  = xcd*64 + (tt >> 1);                 // 64 consecutive rows per XCD
    int w0 = (tt & 1) * 256;
    int tx = threadIdx.x;

    for (int i = tx; i < CC*CC; i += 256) Ms[i] = Mg[i];
    if (tx < 2*CC) { Bs[tx] = Bg[tx]; lws[tx] = lwg[tx]; }
    if (tx < 2) hws[tx] = hwg[tx];

    // stage unaries half-row (coalesced float4 -> LDS)
    {
        const float4* src = (const float4*)(unaries + (size_t)h*ROWF + w0*CC);
        float4* dst = (float4*)lu;
        #pragma unroll
        for (int j = 0; j < 6; ++j) {
            int idx = j*256 + tx;
            if (idx < HROWF/4) dst[idx] = src[idx];
        }
    }

    // build vertically-blurred tile straight from sm (fused vblur)
    for (int idx = tx; idx < CC*264; idx += 256) {
        int c = idx / 264;
        int j = idx - c*264;
        int gw = w0 + j - 4;
        float acc = 0.f;
        if (gw >= 0 && gw < WW) {
            const float* col = sm + (size_t)c*HWSZ + gw;
            #pragma unroll
            for (int t = 0; t < 9; ++t) {
                int hh = h + t - 4;
                if (hh >= 0 && hh < HH) acc += kk.k[t] * col[hh*WW];
            }
        }
        tile[c][j] = acc;
    }
    __syncthreads();

    int w = w0 + tx;
    int p = h*WW + w;

    // horizontal blur -> the ONLY per-thread register array
    float b[CC];
    #pragma unroll
    for (int c = 0; c < CC; ++c) {
        float a = 0.f;
        #pragma unroll
        for (int t = 0; t < 9; ++t) a += kk.k[t] * tile[c][tx + t];
        b[c] = a;
    }

    // separable norm = s(h)*s(w)
    float sv = 0.f, swn = 0.f;
    #pragma unroll
    for (int t = 0; t < 9; ++t) {
        int hh = h + t - 4; if (hh >= 0 && hh < HH) sv  += kk.k[t];
        int wi = w + t - 4; if (wi >= 0 && wi < WW) swn += kk.k[t];
    }
    float invnorm = 1.f / (sv * swn);

    int idxv = sp_indices[iter];
    int lab  = spT[p];                      // coalesced (pre-transposed)
    float hw0 = hws[0], hw1 = hws[1];

    for (int c = 0; c < CC; ++c) {
        float pw = 0.f;
        #pragma unroll
        for (int k = 0; k < CC; ++k) pw += Ms[c*CC + k] * b[k];
        pw *= invnorm;

        float smv = sm[(size_t)c*HWSZ + p];
        float qm  = (smv == 0.f) ? 1.f : smv;
        float ft1 = (lab == idxv)     ? Bs[c]      / qm : 0.f;
        float ft2 = (lab == idxv + 1) ? Bs[CC + c] / qm : 0.f;
        float fta = ft1 + ft2;              // masks disjoint
        float att = lws[c]*ft1 + hw0*(1.f - ft1) + lws[CC + c]*fta + hw1*(1.f - fta);

        float uv = lu[tx*CC + c];           // 21 & 32 coprime -> 2-way = free
        float qn = uv - pw - att;
        if (last) lu[tx*CC + c] = qn;       // reuse staging buffer for HWC out
        else      qout[(size_t)c*HWSZ + p] = qn;
    }
    if (last) {
        __syncthreads();
        float4* dst = (float4*)(outHWC + (size_t)h*ROWF + w0*CC);
        const float4* src = (const float4*)lu;
        #pragma unroll
        for (int j = 0; j < 6; ++j) {
            int idx = j*256 + tx;
            if (idx < HROWF/4) dst[idx] = src[idx];
        }
    }
}

extern "C" void kernel_launch(void* const* d_in, const int* in_sizes, int n_in,
                              void* d_out, int out_size, void* d_ws, size_t ws_size,
                              hipStream_t stream) {
    const float* unaries    = (const float*)d_in[0];
    // d_in[1] = rgb (unused by the reference)
    const int*   sp_map     = (const int*)d_in[2];
    const int*   sp_indices = (const int*)d_in[3];
    const float* skw        = (const float*)d_in[4];
    const float* bkw        = (const float*)d_in[5];
    const float* cm         = (const float*)d_in[6];
    const float* lw         = (const float*)d_in[7];
    const float* hwt        = (const float*)d_in[8];
    float* out = (float*)d_out;

    float* ws   = (float*)d_ws;
    float* buf0 = ws;                    // q  (q_old overwritten by q_new in final)
    float* buf1 = ws + CHW;              // sm
    float* M    = ws + 2*(size_t)CHW;    // 441
    float* B    = M + CC*CC;             // 42 (+pad)
    float* part = B + 64;                // SBLOCKS*44
    int*   spT  = (int*)(part + SBLOCKS*44);   // HWSZ ints

    // 9-tap normalized Gaussian, sigma=3 (fp32, matches reference)
    K9 kk;
    {
        float s = 0.f;
        for (int t = 0; t < 9; ++t) {
            float x = (float)(t - 4) / 3.0f;
            kk.k[t] = expf(-0.5f * x * x);
            s += kk.k[t];
        }
        for (int t = 0; t < 9; ++t) kk.k[t] /= s;
    }

    init_q_kernel<<<HH, 512, 0, stream>>>(unaries, buf0);
    transpose_sp_kernel<<<HWSZ/256, 256, 0, stream>>>(sp_map, spT);
    precomp_M_kernel<<<2, 256, 0, stream>>>(skw, bkw, cm, M);

    for (int it = 0; it < NITERS; ++it) {
        softmax_reduce_kernel<<<SBLOCKS, 256, 0, stream>>>(buf0, buf1, spT,
                                                           sp_indices, it, part);
        finalize_kernel<<<1, 256, 0, stream>>>(part, B);
        int last = (it == NITERS - 1);
        final_kernel<<<1024, 256, 0, stream>>>(buf1, buf0, out, unaries, spT,
                                               sp_indices, it, M, B, lw, hwt, kk, last);
    }
}

// Round 6
// 451.795 us; speedup vs baseline: 2.1479x; 2.1479x over previous
//
#include <hip/hip_runtime.h>
#include <cmath>

#define CC 21
#define HH 512
#define WW 512
#define HWSZ (HH*WW)
#define CHW (CC*HWSZ)
#define NITERS 5
#define SBLOCKS 1024          // softmax_reduce blocks (256 thr each)
#define ROWF (CC*WW)          // 10752 floats per image row in HWC
#define HROWF (CC*256)        // 5376 floats per half row

struct K9 { float k[9]; };

// --- init: q[c,h,w] = unaries[h,w,c]; one block per row, LDS-staged ---
__launch_bounds__(512)
__global__ void init_q_kernel(const float* __restrict__ unaries, float* __restrict__ q) {
    __shared__ __align__(16) float lu[ROWF];
    int h = blockIdx.x, tx = threadIdx.x;
    const float4* src = (const float4*)(unaries + (size_t)h*ROWF);
    float4* dst = (float4*)lu;
    #pragma unroll
    for (int j = 0; j < 6; ++j) {
        int idx = j*512 + tx;
        if (idx < ROWF/4) dst[idx] = src[idx];
    }
    __syncthreads();
    #pragma unroll
    for (int c = 0; c < CC; ++c) q[c*HWSZ + h*WW + tx] = lu[tx*CC + c];
}

// spT[h*W + w] = sp_map[w*W + h]  (one-time; coalesced mask reads later)
__global__ void transpose_sp_kernel(const int* __restrict__ sp, int* __restrict__ spT) {
    int p = blockIdx.x*256 + threadIdx.x;
    int h = p >> 9, w = p & (WW - 1);
    spT[p] = sp[w*WW + h];
}

// M = CM @ (SKW + BKW)   (both blurs identical since theta_gamma==theta_beta)
__global__ void precomp_M_kernel(const float* __restrict__ skw, const float* __restrict__ bkw,
                                 const float* __restrict__ cm, float* __restrict__ M) {
    int i = blockIdx.x * blockDim.x + threadIdx.x;
    if (i >= CC*CC) return;
    int r = i / CC, k = i - r*CC;
    float a = 0.f;
    for (int j = 0; j < CC; ++j) a += cm[r*CC + j] * (skw[j*CC + k] + bkw[j*CC + k]);
    M[i] = a;
}

// softmax + fused sparse clique reduction.
// part layout SLOT-MAJOR: part[t*SBLOCKS + b], t: 0..20 sum1, 21..41 sum2, 42 n1, 43 n2
__launch_bounds__(256)
__global__ void softmax_reduce_kernel(const float* __restrict__ q, float* __restrict__ sm,
                                      const int* __restrict__ spT,
                                      const int* __restrict__ sp_indices, int iter,
                                      float* __restrict__ part) {
    __shared__ float acc[44];
    int tx = threadIdx.x;
    int p = blockIdx.x * 256 + tx;
    if (tx < 44) acc[tx] = 0.f;
    __syncthreads();

    float v[CC];
    float m = -1e30f;
    #pragma unroll
    for (int c = 0; c < CC; ++c) { v[c] = q[c*HWSZ + p]; m = fmaxf(m, v[c]); }
    float s = 0.f;
    #pragma unroll
    for (int c = 0; c < CC; ++c) { v[c] = expf(v[c] - m); s += v[c]; }
    float inv = 1.f / s;
    #pragma unroll
    for (int c = 0; c < CC; ++c) sm[c*HWSZ + p] = v[c] * inv;

    int idx = sp_indices[iter];
    int lab = spT[p];
    if (lab == idx || lab == idx + 1) {
        int mk = (lab == idx) ? 0 : 1;
        atomicAdd(&acc[42 + mk], 1.f);
        for (int c = 0; c < CC; ++c) atomicAdd(&acc[mk*21 + c], expf(v[c] * inv));
    }
    __syncthreads();
    if (tx < 44) part[tx*SBLOCKS + blockIdx.x] = acc[tx];
}

// 42 blocks; block t sums slot t and its count slot 42+(t/21), coalesced.
__launch_bounds__(256)
__global__ void finalize_kernel(const float* __restrict__ part, float* __restrict__ B) {
    __shared__ float rs[256], rn[256];
    int t = blockIdx.x;          // 0..41
    int m = t / 21;
    int tid = threadIdx.x;
    float s = 0.f, n = 0.f;
    for (int b = tid; b < SBLOCKS; b += 256) {
        s += part[t*SBLOCKS + b];
        n += part[(42 + m)*SBLOCKS + b];
    }
    rs[tid] = s; rn[tid] = n;
    __syncthreads();
    for (int off = 128; off > 0; off >>= 1) {
        if (tid < off) { rs[tid] += rs[tid+off]; rn[tid] += rn[tid+off]; }
        __syncthreads();
    }
    if (tid == 0) B[t] = logf((float)HWSZ - rn[0] + rs[0]);
}

// vertical 9-tap blur, zero pad. Half-row blocks, XCD-chunked rows.
__launch_bounds__(256)
__global__ void vblur_kernel(const float* __restrict__ sm, float* __restrict__ tmp, K9 kk) {
    int bid = blockIdx.x;
    int c = bid >> 10;                 // 1024 half-rows per plane
    int r = bid & 1023;
    int xcd = r & 7, tt = r >> 3;
    int h  = xcd*64 + (tt >> 1);
    int w0 = (tt & 1) << 8;
    int w  = w0 + threadIdx.x;
    const float* col = sm + (size_t)c*HWSZ + w;
    float acc = 0.f;
    #pragma unroll
    for (int t = 0; t < 9; ++t) {
        int hh = h + t - 4;
        if (hh >= 0 && hh < HH) acc += kk.k[t] * col[hh*WW];
    }
    tmp[(size_t)c*HWSZ + h*WW + w] = acc;
}

// Fused: hblur (LDS tile from tmp) -> /norm -> M@ -> attachment -> q = u - pw - att
// qout aliases sm IN-PLACE (each thread reads sm[c,p] then writes q[c,p], same
// address, same thread, read-before-write per c) -> no restrict on these two.
__launch_bounds__(256)
__global__ void final_kernel(const float* __restrict__ tmp, const float* sm,
                             float* qout, float* __restrict__ outHWC,
                             const float* __restrict__ unaries,
                             const int* __restrict__ spT,
                             const int* __restrict__ sp_indices, int iter,
                             const float* __restrict__ Mg, const float* __restrict__ Bg,
                             const float* __restrict__ lwg, const float* __restrict__ hwg,
                             K9 kk, int last) {
    __shared__ __align__(16) float lu[HROWF];    // 21504 B (u half-row; out on last)
    __shared__ float tile[CC][264];              // 22176 B (tmp row, w-haloed)
    __shared__ float Ms[CC*CC];
    __shared__ float Bs[2*CC], lws[2*CC], hws[2];

    int bid = blockIdx.x;                        // 0..1023
    int xcd = bid & 7, tt = bid >> 3;
    int h  = xcd*64 + (tt >> 1);
    int w0 = (tt & 1) << 8;
    int tx = threadIdx.x;

    for (int i = tx; i < CC*CC; i += 256) Ms[i] = Mg[i];
    if (tx < 2*CC) { Bs[tx] = Bg[tx]; lws[tx] = lwg[tx]; }
    if (tx < 2) hws[tx] = hwg[tx];

    // stage unaries half-row (coalesced float4 -> LDS)
    {
        const float4* src = (const float4*)(unaries + (size_t)h*ROWF + w0*CC);
        float4* dst = (float4*)lu;
        #pragma unroll
        for (int j = 0; j < 6; ++j) {
            int idx = j*256 + tx;
            if (idx < HROWF/4) dst[idx] = src[idx];
        }
    }

    // stage haloed tmp row tile (22 coalesced loads/thread)
    const float* trow = tmp + (size_t)h*WW;
    for (int idx = tx; idx < CC*264; idx += 256) {
        int c = idx / 264;
        int j = idx - c*264;
        int gw = w0 + j - 4;
        tile[c][j] = (gw >= 0 && gw < WW) ? trow[(size_t)c*HWSZ + gw] : 0.f;
    }
    __syncthreads();

    int w = w0 + tx;
    int p = h*WW + w;

    // horizontal blur -> the ONLY per-thread register array
    float b[CC];
    #pragma unroll
    for (int c = 0; c < CC; ++c) {
        float a = 0.f;
        #pragma unroll
        for (int t = 0; t < 9; ++t) a += kk.k[t] * tile[c][tx + t];
        b[c] = a;
    }

    // separable norm = s(h)*s(w)
    float sv = 0.f, swn = 0.f;
    #pragma unroll
    for (int t = 0; t < 9; ++t) {
        int hh = h + t - 4; if (hh >= 0 && hh < HH) sv  += kk.k[t];
        int wi = w + t - 4; if (wi >= 0 && wi < WW) swn += kk.k[t];
    }
    float invnorm = 1.f / (sv * swn);

    int idxv = sp_indices[iter];
    int lab  = spT[p];                      // coalesced (pre-transposed)
    float hw0 = hws[0], hw1 = hws[1];

    for (int c = 0; c < CC; ++c) {
        float pw = 0.f;
        #pragma unroll
        for (int k = 0; k < CC; ++k) pw += Ms[c*CC + k] * b[k];
        pw *= invnorm;

        float smv = sm[(size_t)c*HWSZ + p];
        float qm  = (smv == 0.f) ? 1.f : smv;
        float ft1 = (lab == idxv)     ? Bs[c]      / qm : 0.f;
        float ft2 = (lab == idxv + 1) ? Bs[CC + c] / qm : 0.f;
        float fta = ft1 + ft2;              // masks disjoint
        float att = lws[c]*ft1 + hw0*(1.f - ft1) + lws[CC + c]*fta + hw1*(1.f - fta);

        float uv = lu[tx*CC + c];           // 21 & 32 coprime -> 2-way = free
        float qn = uv - pw - att;
        if (last) lu[tx*CC + c] = qn;       // reuse staging buffer for HWC out
        else      qout[(size_t)c*HWSZ + p] = qn;
    }
    if (last) {
        __syncthreads();
        float4* dst = (float4*)(outHWC + (size_t)h*ROWF + w0*CC);
        const float4* src = (const float4*)lu;
        #pragma unroll
        for (int j = 0; j < 6; ++j) {
            int idx = j*256 + tx;
            if (idx < HROWF/4) dst[idx] = src[idx];
        }
    }
}

extern "C" void kernel_launch(void* const* d_in, const int* in_sizes, int n_in,
                              void* d_out, int out_size, void* d_ws, size_t ws_size,
                              hipStream_t stream) {
    const float* unaries    = (const float*)d_in[0];
    // d_in[1] = rgb (unused by the reference)
    const int*   sp_map     = (const int*)d_in[2];
    const int*   sp_indices = (const int*)d_in[3];
    const float* skw        = (const float*)d_in[4];
    const float* bkw        = (const float*)d_in[5];
    const float* cm         = (const float*)d_in[6];
    const float* lw         = (const float*)d_in[7];
    const float* hwt        = (const float*)d_in[8];
    float* out = (float*)d_out;

    float* ws   = (float*)d_ws;
    float* bufA = ws;                    // q0 / tmp / ...
    float* bufB = ws + CHW;              // sm / q1 / ...
    float* M    = ws + 2*(size_t)CHW;    // 441
    float* B    = M + CC*CC;             // 42 (+pad)
    float* part = B + 64;                // 44*SBLOCKS (slot-major)
    int*   spT  = (int*)(part + 44*SBLOCKS);   // HWSZ ints

    // 9-tap normalized Gaussian, sigma=3 (fp32, matches reference)
    K9 kk;
    {
        float s = 0.f;
        for (int t = 0; t < 9; ++t) {
            float x = (float)(t - 4) / 3.0f;
            kk.k[t] = expf(-0.5f * x * x);
            s += kk.k[t];
        }
        for (int t = 0; t < 9; ++t) kk.k[t] /= s;
    }

    init_q_kernel<<<HH, 512, 0, stream>>>(unaries, bufA);
    transpose_sp_kernel<<<HWSZ/256, 256, 0, stream>>>(sp_map, spT);
    precomp_M_kernel<<<2, 256, 0, stream>>>(skw, bkw, cm, M);

    float* qb = bufA;      // current q
    float* sb = bufB;      // scratch for sm / q_new
    for (int it = 0; it < NITERS; ++it) {
        softmax_reduce_kernel<<<SBLOCKS, 256, 0, stream>>>(qb, sb, spT,
                                                           sp_indices, it, part);
        finalize_kernel<<<42, 256, 0, stream>>>(part, B);
        vblur_kernel<<<CC*1024, 256, 0, stream>>>(sb, qb, kk);   // tmp over dead q
        int last = (it == NITERS - 1);
        final_kernel<<<1024, 256, 0, stream>>>(qb, sb, sb, out, unaries, spT,
                                               sp_indices, it, M, B, lw, hwt, kk, last);
        float* t_ = qb; qb = sb; sb = t_;                        // q_new now in sb->qb
    }
}